// Round 1
// baseline (1307.980 us; speedup 1.0000x reference)
//
#include <hip/hip_runtime.h>
#include <hip/hip_bf16.h>

#define F 64
#define GRAPHS 512
#define CLASSES 10
#define SCAN_T 1024

// ---------------- CSR build ----------------

__global__ void deg_kernel(const int* __restrict__ ei, int E, int N, int* __restrict__ deg) {
    int i = blockIdx.x * blockDim.x + threadIdx.x;
    int tot = E + N;
    if (i >= tot) return;
    int d = (i < E) ? ei[E + i] : (i - E);
    atomicAdd(&deg[d], 1);
}

__global__ void scan_partial(const int* __restrict__ deg, int N, int* __restrict__ partial) {
    int t = blockIdx.x * blockDim.x + threadIdx.x;   // 0..1023
    int chunk = (N + SCAN_T - 1) / SCAN_T;
    int b = t * chunk;
    int e = min(N, b + chunk);
    int s = 0;
    for (int i = b; i < e; ++i) s += deg[i];
    partial[t] = s;
}

__global__ void scan_block(int* __restrict__ partial) {   // 1 block, 1024 threads
    __shared__ int wsum[16];
    int t = threadIdx.x;
    int lane = t & 63, w = t >> 6;
    int orig = partial[t];
    int v = orig;
    #pragma unroll
    for (int o = 1; o < 64; o <<= 1) {
        int u = __shfl_up(v, o);
        if (lane >= o) v += u;
    }
    if (lane == 63) wsum[w] = v;
    __syncthreads();
    if (t == 0) {
        int run = 0;
        for (int i = 0; i < 16; ++i) { int x = wsum[i]; wsum[i] = run; run += x; }
    }
    __syncthreads();
    v += wsum[w];
    partial[t] = v - orig;   // exclusive prefix
}

__global__ void scan_final(const int* __restrict__ deg, const int* __restrict__ partial,
                           int N, int* __restrict__ rowptr, int* __restrict__ fill) {
    int t = blockIdx.x * blockDim.x + threadIdx.x;
    int chunk = (N + SCAN_T - 1) / SCAN_T;
    int b = t * chunk;
    int e = min(N, b + chunk);
    int run = partial[t];
    for (int i = b; i < e; ++i) {
        rowptr[i] = run;
        fill[i] = run;
        run += deg[i];
    }
    if (t == SCAN_T - 1) rowptr[N] = run;
}

__global__ void scatter_kernel(const int* __restrict__ ei, int E, int N,
                               int* __restrict__ fill, int* __restrict__ csr_src) {
    int i = blockIdx.x * blockDim.x + threadIdx.x;
    int tot = E + N;
    if (i >= tot) return;
    int s, d;
    if (i < E) { s = ei[i]; d = ei[E + i]; }
    else       { s = d = i - E; }
    int pos = atomicAdd(&fill[d], 1);
    csr_src[pos] = s;
}

// ---------------- GEMM + fused attention score epilogue ----------------
// h = x @ W ; e_src = h @ a_src ; e_dst = h @ a_dst
template<int K>
__global__ void gemm_fused(const float* __restrict__ x, const float* __restrict__ W,
                           const float* __restrict__ asrc, const float* __restrict__ adst,
                           float* __restrict__ h, float* __restrict__ es, float* __restrict__ ed,
                           int N) {
    constexpr int ROWS = 16;
    __shared__ float Ws[K * F];
    __shared__ float xs[ROWS * K];
    int base = blockIdx.x * ROWS;
    for (int i = threadIdx.x; i < K * F; i += 256) Ws[i] = W[i];
    int nrows = min(ROWS, N - base);
    for (int i = threadIdx.x; i < nrows * K; i += 256) {
        int r = i / K, c = i - r * K;
        xs[i] = x[(size_t)(base + r) * K + c];
    }
    __syncthreads();
    int wave = threadIdx.x >> 6, lane = threadIdx.x & 63;
    float as_l = asrc[lane];
    float ad_l = adst[lane];
    for (int r = wave; r < nrows; r += 4) {
        float acc = 0.f;
        const float* xr = &xs[r * K];
        #pragma unroll 16
        for (int k = 0; k < K; ++k) acc = fmaf(xr[k], Ws[k * F + lane], acc);
        h[(size_t)(base + r) * F + lane] = acc;
        float vs = acc * as_l;
        float vd = acc * ad_l;
        #pragma unroll
        for (int o = 32; o > 0; o >>= 1) {
            vs += __shfl_down(vs, o);
            vd += __shfl_down(vd, o);
        }
        if (lane == 0) { es[base + r] = vs; ed[base + r] = vd; }
    }
}

// ---------------- per-node segment softmax + aggregation ----------------
// one wave per node; lane = output feature
__global__ void gat_aggregate(const float* __restrict__ h, const float* __restrict__ es,
                              const float* __restrict__ ed, const int* __restrict__ rowptr,
                              const int* __restrict__ csr_src, const float* __restrict__ bias,
                              float* __restrict__ xout, int N) {
    int wave = threadIdx.x >> 6, lane = threadIdx.x & 63;
    int node = blockIdx.x * 4 + wave;
    if (node >= N) return;
    int beg = rowptr[node], end = rowptr[node + 1];
    float edn = ed[node];
    // pass 1: max over incoming edges (distributed over lanes)
    float m = -1e30f;
    for (int j = beg + lane; j < end; j += 64) {
        float e = es[csr_src[j]] + edn;
        e = e > 0.f ? e : 0.2f * e;
        m = fmaxf(m, e);
    }
    #pragma unroll
    for (int o = 32; o > 0; o >>= 1) m = fmaxf(m, __shfl_xor(m, o));
    // pass 2: weighted aggregation (all lanes walk edges together)
    float acc = 0.f, den = 0.f;
    for (int j = beg; j < end; ++j) {
        int s = csr_src[j];
        float e = es[s] + edn;
        e = e > 0.f ? e : 0.2f * e;
        float w = __expf(e - m);
        den += w;
        acc = fmaf(w, h[(size_t)s * F + lane], acc);
    }
    float v = acc / (den + 1e-16f) + bias[lane];
    v = v > 0.f ? v : 0.f;   // relu
    xout[(size_t)node * F + lane] = v;
}

// ---------------- mean pooling over sorted batch ----------------
__global__ void pool_kernel(const float* __restrict__ x1, const float* __restrict__ x2,
                            const float* __restrict__ x3, const int* __restrict__ batch,
                            float* __restrict__ pooled, int* __restrict__ cnt, int N) {
    int wave = threadIdx.x >> 6, lane = threadIdx.x & 63;
    int node = blockIdx.x * 4 + wave;
    if (node >= N) return;
    int g = batch[node];
    atomicAdd(&pooled[g * 192 + lane],        x1[(size_t)node * F + lane]);
    atomicAdd(&pooled[g * 192 + 64 + lane],   x2[(size_t)node * F + lane]);
    atomicAdd(&pooled[g * 192 + 128 + lane],  x3[(size_t)node * F + lane]);
    if (lane == 0) atomicAdd(&cnt[g], 1);
}

// ---------------- final linear + softmax ----------------
__global__ void head_kernel(const float* __restrict__ pooled, const int* __restrict__ cnt,
                            const float* __restrict__ Wo, const float* __restrict__ bo,
                            float* __restrict__ out) {
    int g = blockIdx.x * blockDim.x + threadIdx.x;
    if (g >= GRAPHS) return;
    float inv = 1.0f / fmaxf((float)cnt[g], 1.0f);
    float acc[CLASSES];
    #pragma unroll
    for (int c = 0; c < CLASSES; ++c) acc[c] = bo[c];
    for (int f = 0; f < 192; ++f) {
        float p = pooled[g * 192 + f] * inv;
        #pragma unroll
        for (int c = 0; c < CLASSES; ++c) acc[c] = fmaf(p, Wo[f * CLASSES + c], acc[c]);
    }
    float mx = acc[0];
    #pragma unroll
    for (int c = 1; c < CLASSES; ++c) mx = fmaxf(mx, acc[c]);
    float s = 0.f;
    #pragma unroll
    for (int c = 0; c < CLASSES; ++c) { acc[c] = __expf(acc[c] - mx); s += acc[c]; }
    float invs = 1.0f / s;
    #pragma unroll
    for (int c = 0; c < CLASSES; ++c) out[g * CLASSES + c] = acc[c] * invs;
}

extern "C" void kernel_launch(void* const* d_in, const int* in_sizes, int n_in,
                              void* d_out, int out_size, void* d_ws, size_t ws_size,
                              hipStream_t stream) {
    const float* x   = (const float*)d_in[0];
    const int* ei    = (const int*)d_in[1];
    const int* batch = (const int*)d_in[2];
    const float* W1  = (const float*)d_in[3];
    const float* a1s = (const float*)d_in[4];
    const float* a1d = (const float*)d_in[5];
    const float* b1  = (const float*)d_in[6];
    const float* W2  = (const float*)d_in[7];
    const float* a2s = (const float*)d_in[8];
    const float* a2d = (const float*)d_in[9];
    const float* b2  = (const float*)d_in[10];
    const float* W3  = (const float*)d_in[11];
    const float* a3s = (const float*)d_in[12];
    const float* a3d = (const float*)d_in[13];
    const float* b3  = (const float*)d_in[14];
    const float* Wo  = (const float*)d_in[15];
    const float* bo  = (const float*)d_in[16];
    float* out = (float*)d_out;

    const int N = in_sizes[2];          // batch length = #nodes
    const int E = in_sizes[1] / 2;      // edge_index is [2, E]
    const int TOT = E + N;              // with self loops

    // workspace carve-up
    char* p = (char*)d_ws;
    auto alloc = [&](size_t bytes) { char* r = p; p += (bytes + 255) & ~(size_t)255; return r; };
    float* x1     = (float*)alloc((size_t)N * F * 4);
    float* x2     = (float*)alloc((size_t)N * F * 4);
    float* x3     = (float*)alloc((size_t)N * F * 4);
    float* h      = (float*)alloc((size_t)N * F * 4);
    float* es     = (float*)alloc((size_t)N * 4);
    float* ed     = (float*)alloc((size_t)N * 4);
    int* deg      = (int*)alloc((size_t)N * 4);
    int* rowptr   = (int*)alloc((size_t)(N + 1) * 4);
    int* fill     = (int*)alloc((size_t)N * 4);
    int* csr_src  = (int*)alloc((size_t)TOT * 4);
    int* partial  = (int*)alloc((size_t)SCAN_T * 4);
    float* pooled = (float*)alloc((size_t)GRAPHS * 192 * 4);
    int* cnt      = (int*)alloc((size_t)GRAPHS * 4);

    // zero what needs zeroing (ws is poisoned 0xAA before every launch)
    hipMemsetAsync(deg, 0, (size_t)N * 4, stream);
    hipMemsetAsync(pooled, 0, (size_t)GRAPHS * 192 * 4, stream);
    hipMemsetAsync(cnt, 0, (size_t)GRAPHS * 4, stream);

    // CSR build (shared by all 3 layers)
    deg_kernel<<<(TOT + 255) / 256, 256, 0, stream>>>(ei, E, N, deg);
    scan_partial<<<SCAN_T / 256, 256, 0, stream>>>(deg, N, partial);
    scan_block<<<1, SCAN_T, 0, stream>>>(partial);
    scan_final<<<SCAN_T / 256, 256, 0, stream>>>(deg, partial, N, rowptr, fill);
    scatter_kernel<<<(TOT + 255) / 256, 256, 0, stream>>>(ei, E, N, fill, csr_src);

    int gemm_blocks = (N + 15) / 16;
    int node_blocks = (N + 3) / 4;

    // layer 1
    gemm_fused<128><<<gemm_blocks, 256, 0, stream>>>(x, W1, a1s, a1d, h, es, ed, N);
    gat_aggregate<<<node_blocks, 256, 0, stream>>>(h, es, ed, rowptr, csr_src, b1, x1, N);
    // layer 2
    gemm_fused<64><<<gemm_blocks, 256, 0, stream>>>(x1, W2, a2s, a2d, h, es, ed, N);
    gat_aggregate<<<node_blocks, 256, 0, stream>>>(h, es, ed, rowptr, csr_src, b2, x2, N);
    // layer 3
    gemm_fused<64><<<gemm_blocks, 256, 0, stream>>>(x2, W3, a3s, a3d, h, es, ed, N);
    gat_aggregate<<<node_blocks, 256, 0, stream>>>(h, es, ed, rowptr, csr_src, b3, x3, N);

    // readout
    pool_kernel<<<node_blocks, 256, 0, stream>>>(x1, x2, x3, batch, pooled, cnt, N);
    head_kernel<<<(GRAPHS + 255) / 256, 256, 0, stream>>>(pooled, cnt, Wo, bo, out);
}

// Round 2
// 1121.607 us; speedup vs baseline: 1.1662x; 1.1662x over previous
//
#include <hip/hip_runtime.h>
#include <hip/hip_bf16.h>

#define F 64
#define GRAPHS 512
#define CLASSES 10
#define SCAN_T 1024

// ---------------- CSR build ----------------

__global__ void deg_kernel(const int* __restrict__ ei, int E, int N, int* __restrict__ deg) {
    int i = blockIdx.x * blockDim.x + threadIdx.x;
    int tot = E + N;
    if (i >= tot) return;
    int d = (i < E) ? ei[E + i] : (i - E);
    atomicAdd(&deg[d], 1);
}

__global__ void scan_partial(const int* __restrict__ deg, int N, int* __restrict__ partial) {
    int t = blockIdx.x * blockDim.x + threadIdx.x;   // 0..1023
    int chunk = (N + SCAN_T - 1) / SCAN_T;
    int b = t * chunk;
    int e = min(N, b + chunk);
    int s = 0;
    for (int i = b; i < e; ++i) s += deg[i];
    partial[t] = s;
}

__global__ void scan_block(int* __restrict__ partial) {   // 1 block, 1024 threads
    __shared__ int wsum[16];
    int t = threadIdx.x;
    int lane = t & 63, w = t >> 6;
    int orig = partial[t];
    int v = orig;
    #pragma unroll
    for (int o = 1; o < 64; o <<= 1) {
        int u = __shfl_up(v, o);
        if (lane >= o) v += u;
    }
    if (lane == 63) wsum[w] = v;
    __syncthreads();
    if (t == 0) {
        int run = 0;
        for (int i = 0; i < 16; ++i) { int x = wsum[i]; wsum[i] = run; run += x; }
    }
    __syncthreads();
    v += wsum[w];
    partial[t] = v - orig;   // exclusive prefix
}

__global__ void scan_final(const int* __restrict__ deg, const int* __restrict__ partial,
                           int N, int* __restrict__ rowptr, int* __restrict__ fill) {
    int t = blockIdx.x * blockDim.x + threadIdx.x;
    int chunk = (N + SCAN_T - 1) / SCAN_T;
    int b = t * chunk;
    int e = min(N, b + chunk);
    int run = partial[t];
    for (int i = b; i < e; ++i) {
        rowptr[i] = run;
        fill[i] = run;
        run += deg[i];
    }
    if (t == SCAN_T - 1) rowptr[N] = run;
}

__global__ void scatter_kernel(const int* __restrict__ ei, int E, int N,
                               int* __restrict__ fill, int* __restrict__ csr_src) {
    int i = blockIdx.x * blockDim.x + threadIdx.x;
    int tot = E + N;
    if (i >= tot) return;
    int s, d;
    if (i < E) { s = ei[i]; d = ei[E + i]; }
    else       { s = d = i - E; }
    int pos = atomicAdd(&fill[d], 1);
    csr_src[pos] = s;
}

// ---------------- GEMM + fused attention score epilogue ----------------
// h = x @ W ; e_src = h @ a_src ; e_dst = h @ a_dst
template<int K>
__global__ void gemm_fused(const float* __restrict__ x, const float* __restrict__ W,
                           const float* __restrict__ asrc, const float* __restrict__ adst,
                           float* __restrict__ h, float* __restrict__ es, float* __restrict__ ed,
                           int N) {
    constexpr int ROWS = 16;
    __shared__ float Ws[K * F];
    __shared__ float xs[ROWS * K];
    int base = blockIdx.x * ROWS;
    for (int i = threadIdx.x; i < K * F; i += 256) Ws[i] = W[i];
    int nrows = min(ROWS, N - base);
    for (int i = threadIdx.x; i < nrows * K; i += 256) {
        int r = i / K, c = i - r * K;
        xs[i] = x[(size_t)(base + r) * K + c];
    }
    __syncthreads();
    int wave = threadIdx.x >> 6, lane = threadIdx.x & 63;
    float as_l = asrc[lane];
    float ad_l = adst[lane];
    for (int r = wave; r < nrows; r += 4) {
        float acc = 0.f;
        const float* xr = &xs[r * K];
        #pragma unroll 16
        for (int k = 0; k < K; ++k) acc = fmaf(xr[k], Ws[k * F + lane], acc);
        h[(size_t)(base + r) * F + lane] = acc;
        float vs = acc * as_l;
        float vd = acc * ad_l;
        #pragma unroll
        for (int o = 32; o > 0; o >>= 1) {
            vs += __shfl_down(vs, o);
            vd += __shfl_down(vd, o);
        }
        if (lane == 0) { es[base + r] = vs; ed[base + r] = vd; }
    }
}

// ---------------- per-node segment softmax + aggregation ----------------
// one wave per node; lane = output feature
__global__ void gat_aggregate(const float* __restrict__ h, const float* __restrict__ es,
                              const float* __restrict__ ed, const int* __restrict__ rowptr,
                              const int* __restrict__ csr_src, const float* __restrict__ bias,
                              float* __restrict__ xout, int N) {
    int wave = threadIdx.x >> 6, lane = threadIdx.x & 63;
    int node = blockIdx.x * 4 + wave;
    if (node >= N) return;
    int beg = rowptr[node], end = rowptr[node + 1];
    float edn = ed[node];
    // pass 1: max over incoming edges (distributed over lanes)
    float m = -1e30f;
    for (int j = beg + lane; j < end; j += 64) {
        float e = es[csr_src[j]] + edn;
        e = e > 0.f ? e : 0.2f * e;
        m = fmaxf(m, e);
    }
    #pragma unroll
    for (int o = 32; o > 0; o >>= 1) m = fmaxf(m, __shfl_xor(m, o));
    // pass 2: weighted aggregation (all lanes walk edges together)
    float acc = 0.f, den = 0.f;
    for (int j = beg; j < end; ++j) {
        int s = csr_src[j];
        float e = es[s] + edn;
        e = e > 0.f ? e : 0.2f * e;
        float w = __expf(e - m);
        den += w;
        acc = fmaf(w, h[(size_t)s * F + lane], acc);
    }
    float v = acc / (den + 1e-16f) + bias[lane];
    v = v > 0.f ? v : 0.f;   // relu
    xout[(size_t)node * F + lane] = v;
}

// ---------------- graph boundaries (batch is sorted) ----------------
__global__ void gbounds_kernel(const int* __restrict__ batch, int N, int* __restrict__ gstart) {
    int g = blockIdx.x * blockDim.x + threadIdx.x;
    if (g > GRAPHS) return;
    int lo = 0, hi = N;
    while (lo < hi) {
        int mid = (lo + hi) >> 1;
        if (batch[mid] < g) lo = mid + 1; else hi = mid;
    }
    gstart[g] = lo;   // lower_bound(g); gstart[G] == N
}

// ---------------- mean pooling: 4 blocks per graph, register accumulate ----------------
// block = 192 threads (3 waves); thread t owns concat-feature t
__global__ void pool_kernel(const float* __restrict__ x1, const float* __restrict__ x2,
                            const float* __restrict__ x3, const int* __restrict__ gstart,
                            float* __restrict__ pooled) {
    int g = blockIdx.x >> 2;
    int seg = blockIdx.x & 3;
    int f = threadIdx.x;               // 0..191
    int lane = f & 63;
    const float* src = (f < 64) ? x1 : (f < 128) ? x2 : x3;
    int lo = gstart[g], hi = gstart[g + 1];
    int len = hi - lo;
    int chunk = (len + 3) >> 2;
    int b = lo + seg * chunk;
    int e = min(hi, b + chunk);
    float s0 = 0.f, s1 = 0.f, s2 = 0.f, s3 = 0.f;
    int i = b;
    for (; i + 3 < e; i += 4) {
        s0 += src[(size_t)i * F + lane];
        s1 += src[(size_t)(i + 1) * F + lane];
        s2 += src[(size_t)(i + 2) * F + lane];
        s3 += src[(size_t)(i + 3) * F + lane];
    }
    for (; i < e; ++i) s0 += src[(size_t)i * F + lane];
    float s = (s0 + s1) + (s2 + s3);
    atomicAdd(&pooled[g * 192 + f], s);
}

// ---------------- final linear + softmax ----------------
__global__ void head_kernel(const float* __restrict__ pooled, const int* __restrict__ gstart,
                            const float* __restrict__ Wo, const float* __restrict__ bo,
                            float* __restrict__ out) {
    int g = blockIdx.x * blockDim.x + threadIdx.x;
    if (g >= GRAPHS) return;
    int cntg = gstart[g + 1] - gstart[g];
    float inv = 1.0f / fmaxf((float)cntg, 1.0f);
    float acc[CLASSES];
    #pragma unroll
    for (int c = 0; c < CLASSES; ++c) acc[c] = bo[c];
    for (int f = 0; f < 192; ++f) {
        float p = pooled[g * 192 + f] * inv;
        #pragma unroll
        for (int c = 0; c < CLASSES; ++c) acc[c] = fmaf(p, Wo[f * CLASSES + c], acc[c]);
    }
    float mx = acc[0];
    #pragma unroll
    for (int c = 1; c < CLASSES; ++c) mx = fmaxf(mx, acc[c]);
    float s = 0.f;
    #pragma unroll
    for (int c = 0; c < CLASSES; ++c) { acc[c] = __expf(acc[c] - mx); s += acc[c]; }
    float invs = 1.0f / s;
    #pragma unroll
    for (int c = 0; c < CLASSES; ++c) out[g * CLASSES + c] = acc[c] * invs;
}

extern "C" void kernel_launch(void* const* d_in, const int* in_sizes, int n_in,
                              void* d_out, int out_size, void* d_ws, size_t ws_size,
                              hipStream_t stream) {
    const float* x   = (const float*)d_in[0];
    const int* ei    = (const int*)d_in[1];
    const int* batch = (const int*)d_in[2];
    const float* W1  = (const float*)d_in[3];
    const float* a1s = (const float*)d_in[4];
    const float* a1d = (const float*)d_in[5];
    const float* b1  = (const float*)d_in[6];
    const float* W2  = (const float*)d_in[7];
    const float* a2s = (const float*)d_in[8];
    const float* a2d = (const float*)d_in[9];
    const float* b2  = (const float*)d_in[10];
    const float* W3  = (const float*)d_in[11];
    const float* a3s = (const float*)d_in[12];
    const float* a3d = (const float*)d_in[13];
    const float* b3  = (const float*)d_in[14];
    const float* Wo  = (const float*)d_in[15];
    const float* bo  = (const float*)d_in[16];
    float* out = (float*)d_out;

    const int N = in_sizes[2];          // batch length = #nodes
    const int E = in_sizes[1] / 2;      // edge_index is [2, E]
    const int TOT = E + N;              // with self loops

    // workspace carve-up
    char* p = (char*)d_ws;
    auto alloc = [&](size_t bytes) { char* r = p; p += (bytes + 255) & ~(size_t)255; return r; };
    float* x1     = (float*)alloc((size_t)N * F * 4);
    float* x2     = (float*)alloc((size_t)N * F * 4);
    float* x3     = (float*)alloc((size_t)N * F * 4);
    float* h      = (float*)alloc((size_t)N * F * 4);
    float* es     = (float*)alloc((size_t)N * 4);
    float* ed     = (float*)alloc((size_t)N * 4);
    int* deg      = (int*)alloc((size_t)N * 4);
    int* rowptr   = (int*)alloc((size_t)(N + 1) * 4);
    int* fill     = (int*)alloc((size_t)N * 4);
    int* csr_src  = (int*)alloc((size_t)TOT * 4);
    int* partial  = (int*)alloc((size_t)SCAN_T * 4);
    float* pooled = (float*)alloc((size_t)GRAPHS * 192 * 4);
    int* gstart   = (int*)alloc((size_t)(GRAPHS + 1) * 4);

    // zero what needs zeroing (ws is poisoned 0xAA before every launch)
    hipMemsetAsync(deg, 0, (size_t)N * 4, stream);
    hipMemsetAsync(pooled, 0, (size_t)GRAPHS * 192 * 4, stream);

    // CSR build (shared by all 3 layers)
    deg_kernel<<<(TOT + 255) / 256, 256, 0, stream>>>(ei, E, N, deg);
    scan_partial<<<SCAN_T / 256, 256, 0, stream>>>(deg, N, partial);
    scan_block<<<1, SCAN_T, 0, stream>>>(partial);
    scan_final<<<SCAN_T / 256, 256, 0, stream>>>(deg, partial, N, rowptr, fill);
    scatter_kernel<<<(TOT + 255) / 256, 256, 0, stream>>>(ei, E, N, fill, csr_src);
    gbounds_kernel<<<3, 256, 0, stream>>>(batch, N, gstart);

    int gemm_blocks = (N + 15) / 16;
    int node_blocks = (N + 3) / 4;

    // layer 1
    gemm_fused<128><<<gemm_blocks, 256, 0, stream>>>(x, W1, a1s, a1d, h, es, ed, N);
    gat_aggregate<<<node_blocks, 256, 0, stream>>>(h, es, ed, rowptr, csr_src, b1, x1, N);
    // layer 2
    gemm_fused<64><<<gemm_blocks, 256, 0, stream>>>(x1, W2, a2s, a2d, h, es, ed, N);
    gat_aggregate<<<node_blocks, 256, 0, stream>>>(h, es, ed, rowptr, csr_src, b2, x2, N);
    // layer 3
    gemm_fused<64><<<gemm_blocks, 256, 0, stream>>>(x2, W3, a3s, a3d, h, es, ed, N);
    gat_aggregate<<<node_blocks, 256, 0, stream>>>(h, es, ed, rowptr, csr_src, b3, x3, N);

    // readout
    pool_kernel<<<GRAPHS * 4, 192, 0, stream>>>(x1, x2, x3, gstart, pooled);
    head_kernel<<<(GRAPHS + 255) / 256, 256, 0, stream>>>(pooled, gstart, Wo, bo, out);
}

// Round 3
// 822.848 us; speedup vs baseline: 1.5896x; 1.3631x over previous
//
#include <hip/hip_runtime.h>
#include <hip/hip_bf16.h>

#define F 64
#define GRAPHS 512
#define CLASSES 10
#define SCAN_T 1024

// ---------------- CSR build ----------------

__global__ void deg_kernel(const int* __restrict__ ei, int E, int N, int* __restrict__ deg) {
    int i = blockIdx.x * blockDim.x + threadIdx.x;
    int tot = E + N;
    if (i >= tot) return;
    int d = (i < E) ? ei[E + i] : (i - E);
    atomicAdd(&deg[d], 1);
}

__global__ void scan_partial(const int* __restrict__ deg, int N, int* __restrict__ partial) {
    int t = blockIdx.x * blockDim.x + threadIdx.x;   // 0..1023
    int chunk = (N + SCAN_T - 1) / SCAN_T;
    int b = t * chunk;
    int e = min(N, b + chunk);
    int s = 0;
    for (int i = b; i < e; ++i) s += deg[i];
    partial[t] = s;
}

__global__ void scan_block(int* __restrict__ partial) {   // 1 block, 1024 threads
    __shared__ int wsum[16];
    int t = threadIdx.x;
    int lane = t & 63, w = t >> 6;
    int orig = partial[t];
    int v = orig;
    #pragma unroll
    for (int o = 1; o < 64; o <<= 1) {
        int u = __shfl_up(v, o);
        if (lane >= o) v += u;
    }
    if (lane == 63) wsum[w] = v;
    __syncthreads();
    if (t == 0) {
        int run = 0;
        for (int i = 0; i < 16; ++i) { int x = wsum[i]; wsum[i] = run; run += x; }
    }
    __syncthreads();
    v += wsum[w];
    partial[t] = v - orig;   // exclusive prefix
}

__global__ void scan_final(const int* __restrict__ deg, const int* __restrict__ partial,
                           int N, int* __restrict__ rowptr, int* __restrict__ fill) {
    int t = blockIdx.x * blockDim.x + threadIdx.x;
    int chunk = (N + SCAN_T - 1) / SCAN_T;
    int b = t * chunk;
    int e = min(N, b + chunk);
    int run = partial[t];
    for (int i = b; i < e; ++i) {
        rowptr[i] = run;
        fill[i] = run;
        run += deg[i];
    }
    if (t == SCAN_T - 1) rowptr[N] = run;
}

__global__ void scatter_kernel(const int* __restrict__ ei, int E, int N,
                               int* __restrict__ fill, int* __restrict__ csr_src) {
    int i = blockIdx.x * blockDim.x + threadIdx.x;
    int tot = E + N;
    if (i >= tot) return;
    int s, d;
    if (i < E) { s = ei[i]; d = ei[E + i]; }
    else       { s = d = i - E; }
    int pos = atomicAdd(&fill[d], 1);
    csr_src[pos] = s;
}

// ---------------- GEMM + fused attention score epilogue ----------------
// h = x @ W ; e_src = h @ a_src ; e_dst = h @ a_dst
template<int K>
__global__ void gemm_fused(const float* __restrict__ x, const float* __restrict__ W,
                           const float* __restrict__ asrc, const float* __restrict__ adst,
                           float* __restrict__ h, float* __restrict__ es, float* __restrict__ ed,
                           int N) {
    constexpr int ROWS = 16;
    __shared__ float Ws[K * F];
    __shared__ float xs[ROWS * K];
    int base = blockIdx.x * ROWS;
    for (int i = threadIdx.x; i < K * F; i += 256) Ws[i] = W[i];
    int nrows = min(ROWS, N - base);
    for (int i = threadIdx.x; i < nrows * K; i += 256) {
        int r = i / K, c = i - r * K;
        xs[i] = x[(size_t)(base + r) * K + c];
    }
    __syncthreads();
    int wave = threadIdx.x >> 6, lane = threadIdx.x & 63;
    float as_l = asrc[lane];
    float ad_l = adst[lane];
    for (int r = wave; r < nrows; r += 4) {
        float acc = 0.f;
        const float* xr = &xs[r * K];
        #pragma unroll 16
        for (int k = 0; k < K; ++k) acc = fmaf(xr[k], Ws[k * F + lane], acc);
        h[(size_t)(base + r) * F + lane] = acc;
        float vs = acc * as_l;
        float vd = acc * ad_l;
        #pragma unroll
        for (int o = 32; o > 0; o >>= 1) {
            vs += __shfl_down(vs, o);
            vd += __shfl_down(vd, o);
        }
        if (lane == 0) { es[base + r] = vs; ed[base + r] = vd; }
    }
}

// ---------------- per-node segment softmax + aggregation ----------------
// one wave per node; lane = output feature.
// Fast path (deg<=64): lanes cooperatively process edges — parallel gather of
// es, vectorized leaky+exp, wave max/sum reductions; (src,w) pairs broadcast
// through per-wave LDS, h-row FMA loop unrolled x4 with 4 accumulators.
__global__ void gat_aggregate(const float* __restrict__ h, const float* __restrict__ es,
                              const float* __restrict__ ed, const int* __restrict__ rowptr,
                              const int* __restrict__ csr_src, const float* __restrict__ bias,
                              float* __restrict__ xout, int N) {
    __shared__ float2 sw[4][64];
    int wave = threadIdx.x >> 6, lane = threadIdx.x & 63;
    int node = blockIdx.x * 4 + wave;
    if (node >= N) return;
    int beg = rowptr[node], end = rowptr[node + 1];
    int cnt = end - beg;
    float edn = ed[node];
    float acc;

    if (cnt <= 64) {
        int s = 0;
        float e = -1e30f;
        if (lane < cnt) {
            s = csr_src[beg + lane];
            float t = es[s] + edn;
            e = t > 0.f ? t : 0.2f * t;
        }
        float m = e;
        #pragma unroll
        for (int o = 32; o > 0; o >>= 1) m = fmaxf(m, __shfl_xor(m, o));
        float w = (lane < cnt) ? __expf(e - m) : 0.f;
        float den = w;
        #pragma unroll
        for (int o = 32; o > 0; o >>= 1) den += __shfl_xor(den, o);
        sw[wave][lane] = make_float2(__int_as_float(s), w);
        float a0 = 0.f, a1 = 0.f, a2 = 0.f, a3 = 0.f;
        int i = 0;
        for (; i + 3 < cnt; i += 4) {
            float2 p0 = sw[wave][i];
            float2 p1 = sw[wave][i + 1];
            float2 p2 = sw[wave][i + 2];
            float2 p3 = sw[wave][i + 3];
            float h0 = h[(size_t)__float_as_int(p0.x) * F + lane];
            float h1 = h[(size_t)__float_as_int(p1.x) * F + lane];
            float h2 = h[(size_t)__float_as_int(p2.x) * F + lane];
            float h3 = h[(size_t)__float_as_int(p3.x) * F + lane];
            a0 = fmaf(p0.y, h0, a0);
            a1 = fmaf(p1.y, h1, a1);
            a2 = fmaf(p2.y, h2, a2);
            a3 = fmaf(p3.y, h3, a3);
        }
        for (; i < cnt; ++i) {
            float2 p = sw[wave][i];
            a0 = fmaf(p.y, h[(size_t)__float_as_int(p.x) * F + lane], a0);
        }
        acc = ((a0 + a1) + (a2 + a3)) / (den + 1e-16f);
    } else {
        // slow path: strided max, serial accumulate (rare: deg>64)
        float m = -1e30f;
        for (int j = beg + lane; j < end; j += 64) {
            float e = es[csr_src[j]] + edn;
            e = e > 0.f ? e : 0.2f * e;
            m = fmaxf(m, e);
        }
        #pragma unroll
        for (int o = 32; o > 0; o >>= 1) m = fmaxf(m, __shfl_xor(m, o));
        float a = 0.f, den = 0.f;
        for (int j = beg; j < end; ++j) {
            int s = csr_src[j];
            float e = es[s] + edn;
            e = e > 0.f ? e : 0.2f * e;
            float w = __expf(e - m);
            den += w;
            a = fmaf(w, h[(size_t)s * F + lane], a);
        }
        acc = a / (den + 1e-16f);
    }
    float v = acc + bias[lane];
    v = v > 0.f ? v : 0.f;   // relu
    xout[(size_t)node * F + lane] = v;
}

// ---------------- graph boundaries (batch is sorted) ----------------
__global__ void gbounds_kernel(const int* __restrict__ batch, int N, int* __restrict__ gstart) {
    int g = blockIdx.x * blockDim.x + threadIdx.x;
    if (g > GRAPHS) return;
    int lo = 0, hi = N;
    while (lo < hi) {
        int mid = (lo + hi) >> 1;
        if (batch[mid] < g) lo = mid + 1; else hi = mid;
    }
    gstart[g] = lo;   // lower_bound(g); gstart[G] == N
}

// ---------------- mean pooling: 4 blocks per graph, register accumulate ----------------
// block = 192 threads (3 waves); thread t owns concat-feature t
__global__ void pool_kernel(const float* __restrict__ x1, const float* __restrict__ x2,
                            const float* __restrict__ x3, const int* __restrict__ gstart,
                            float* __restrict__ pooled) {
    int g = blockIdx.x >> 2;
    int seg = blockIdx.x & 3;
    int f = threadIdx.x;               // 0..191
    int lane = f & 63;
    const float* src = (f < 64) ? x1 : (f < 128) ? x2 : x3;
    int lo = gstart[g], hi = gstart[g + 1];
    int len = hi - lo;
    int chunk = (len + 3) >> 2;
    int b = lo + seg * chunk;
    int e = min(hi, b + chunk);
    float s0 = 0.f, s1 = 0.f, s2 = 0.f, s3 = 0.f;
    int i = b;
    for (; i + 3 < e; i += 4) {
        s0 += src[(size_t)i * F + lane];
        s1 += src[(size_t)(i + 1) * F + lane];
        s2 += src[(size_t)(i + 2) * F + lane];
        s3 += src[(size_t)(i + 3) * F + lane];
    }
    for (; i < e; ++i) s0 += src[(size_t)i * F + lane];
    float s = (s0 + s1) + (s2 + s3);
    atomicAdd(&pooled[g * 192 + f], s);
}

// ---------------- final linear + softmax ----------------
__global__ void head_kernel(const float* __restrict__ pooled, const int* __restrict__ gstart,
                            const float* __restrict__ Wo, const float* __restrict__ bo,
                            float* __restrict__ out) {
    int g = blockIdx.x * blockDim.x + threadIdx.x;
    if (g >= GRAPHS) return;
    int cntg = gstart[g + 1] - gstart[g];
    float inv = 1.0f / fmaxf((float)cntg, 1.0f);
    float acc[CLASSES];
    #pragma unroll
    for (int c = 0; c < CLASSES; ++c) acc[c] = bo[c];
    for (int f = 0; f < 192; ++f) {
        float p = pooled[g * 192 + f] * inv;
        #pragma unroll
        for (int c = 0; c < CLASSES; ++c) acc[c] = fmaf(p, Wo[f * CLASSES + c], acc[c]);
    }
    float mx = acc[0];
    #pragma unroll
    for (int c = 1; c < CLASSES; ++c) mx = fmaxf(mx, acc[c]);
    float s = 0.f;
    #pragma unroll
    for (int c = 0; c < CLASSES; ++c) { acc[c] = __expf(acc[c] - mx); s += acc[c]; }
    float invs = 1.0f / s;
    #pragma unroll
    for (int c = 0; c < CLASSES; ++c) out[g * CLASSES + c] = acc[c] * invs;
}

extern "C" void kernel_launch(void* const* d_in, const int* in_sizes, int n_in,
                              void* d_out, int out_size, void* d_ws, size_t ws_size,
                              hipStream_t stream) {
    const float* x   = (const float*)d_in[0];
    const int* ei    = (const int*)d_in[1];
    const int* batch = (const int*)d_in[2];
    const float* W1  = (const float*)d_in[3];
    const float* a1s = (const float*)d_in[4];
    const float* a1d = (const float*)d_in[5];
    const float* b1  = (const float*)d_in[6];
    const float* W2  = (const float*)d_in[7];
    const float* a2s = (const float*)d_in[8];
    const float* a2d = (const float*)d_in[9];
    const float* b2  = (const float*)d_in[10];
    const float* W3  = (const float*)d_in[11];
    const float* a3s = (const float*)d_in[12];
    const float* a3d = (const float*)d_in[13];
    const float* b3  = (const float*)d_in[14];
    const float* Wo  = (const float*)d_in[15];
    const float* bo  = (const float*)d_in[16];
    float* out = (float*)d_out;

    const int N = in_sizes[2];          // batch length = #nodes
    const int E = in_sizes[1] / 2;      // edge_index is [2, E]
    const int TOT = E + N;              // with self loops

    // workspace carve-up
    char* p = (char*)d_ws;
    auto alloc = [&](size_t bytes) { char* r = p; p += (bytes + 255) & ~(size_t)255; return r; };
    float* x1     = (float*)alloc((size_t)N * F * 4);
    float* x2     = (float*)alloc((size_t)N * F * 4);
    float* x3     = (float*)alloc((size_t)N * F * 4);
    float* h      = (float*)alloc((size_t)N * F * 4);
    float* es     = (float*)alloc((size_t)N * 4);
    float* ed     = (float*)alloc((size_t)N * 4);
    int* deg      = (int*)alloc((size_t)N * 4);
    int* rowptr   = (int*)alloc((size_t)(N + 1) * 4);
    int* fill     = (int*)alloc((size_t)N * 4);
    int* csr_src  = (int*)alloc((size_t)TOT * 4);
    int* partial  = (int*)alloc((size_t)SCAN_T * 4);
    float* pooled = (float*)alloc((size_t)GRAPHS * 192 * 4);
    int* gstart   = (int*)alloc((size_t)(GRAPHS + 1) * 4);

    // zero what needs zeroing (ws is poisoned 0xAA before every launch)
    hipMemsetAsync(deg, 0, (size_t)N * 4, stream);
    hipMemsetAsync(pooled, 0, (size_t)GRAPHS * 192 * 4, stream);

    // CSR build (shared by all 3 layers)
    deg_kernel<<<(TOT + 255) / 256, 256, 0, stream>>>(ei, E, N, deg);
    scan_partial<<<SCAN_T / 256, 256, 0, stream>>>(deg, N, partial);
    scan_block<<<1, SCAN_T, 0, stream>>>(partial);
    scan_final<<<SCAN_T / 256, 256, 0, stream>>>(deg, partial, N, rowptr, fill);
    scatter_kernel<<<(TOT + 255) / 256, 256, 0, stream>>>(ei, E, N, fill, csr_src);
    gbounds_kernel<<<3, 256, 0, stream>>>(batch, N, gstart);

    int gemm_blocks = (N + 15) / 16;
    int node_blocks = (N + 3) / 4;

    // layer 1
    gemm_fused<128><<<gemm_blocks, 256, 0, stream>>>(x, W1, a1s, a1d, h, es, ed, N);
    gat_aggregate<<<node_blocks, 256, 0, stream>>>(h, es, ed, rowptr, csr_src, b1, x1, N);
    // layer 2
    gemm_fused<64><<<gemm_blocks, 256, 0, stream>>>(x1, W2, a2s, a2d, h, es, ed, N);
    gat_aggregate<<<node_blocks, 256, 0, stream>>>(h, es, ed, rowptr, csr_src, b2, x2, N);
    // layer 3
    gemm_fused<64><<<gemm_blocks, 256, 0, stream>>>(x2, W3, a3s, a3d, h, es, ed, N);
    gat_aggregate<<<node_blocks, 256, 0, stream>>>(h, es, ed, rowptr, csr_src, b3, x3, N);

    // readout
    pool_kernel<<<GRAPHS * 4, 192, 0, stream>>>(x1, x2, x3, gstart, pooled);
    head_kernel<<<(GRAPHS + 255) / 256, 256, 0, stream>>>(pooled, gstart, Wo, bo, out);
}